// Round 4
// baseline (853.177 us; speedup 1.0000x reference)
//
#include <hip/hip_runtime.h>
#include <math.h>

// Problem constants (match reference)
#define NB   16      // batch
#define SL   4096    // sequence length
#define D    1024    // all dims are 1024
#define NCH  64      // s-chunks for weighted-value partial sums
#define ROWS_PER_CH (SL / NCH)   // 64

__device__ __forceinline__ float wave_reduce_sum(float v) {
    #pragma unroll
    for (int m = 32; m >= 1; m >>= 1) v += __shfl_xor(v, m, 64);
    return v;
}

// ---------------------------------------------------------------------------
// K1: q[b,h] = sum_j query[b,j] * Wq[j,h]        (16x1024 outputs)
__global__ void qproj_kernel(const float* __restrict__ query,
                             const float* __restrict__ Wq,
                             float* __restrict__ q) {
    int b = blockIdx.x >> 2;
    int h = ((blockIdx.x & 3) << 8) + threadIdx.x;
    const float* qr = query + b * D;
    float acc = 0.f;
    #pragma unroll 4
    for (int j = 0; j < D; ++j) acc += qr[j] * Wq[j * D + h];
    q[b * D + h] = acc;
}

// ---------------------------------------------------------------------------
// K2: qk[b,i] = sum_h Wk[i,h] * q[b,h]           (16x1024 outputs)
__global__ void kvec_kernel(const float* __restrict__ Wk,
                            const float* __restrict__ q,
                            float* __restrict__ qk) {
    int b  = blockIdx.x >> 2;
    int r0 = (blockIdx.x & 3) << 8;   // 256 rows per block
    __shared__ float qs[D];
    for (int t = threadIdx.x; t < D; t += 256) qs[t] = q[b * D + t];
    __syncthreads();
    int wave = threadIdx.x >> 6, lane = threadIdx.x & 63;
    for (int r = wave; r < 256; r += 4) {
        int i = r0 + r;
        const float* row = Wk + (size_t)i * D;
        float acc = 0.f;
        #pragma unroll 4
        for (int c = lane; c < D; c += 64) acc += row[c] * qs[c];
        acc = wave_reduce_sum(acc);
        if (lane == 0) qk[b * D + i] = acc;
    }
}

// ---------------------------------------------------------------------------
// K3: scores[b,s] = key[b,s,:] . qk[b,:] / 32    (the 256 MB key stream)
__global__ void scores_kernel(const float* __restrict__ key,
                              const float* __restrict__ qk,
                              float* __restrict__ scores) {
    int b  = blockIdx.x / (SL / 4);
    int s0 = (blockIdx.x % (SL / 4)) * 4;
    __shared__ float4 qs[D / 4];
    qs[threadIdx.x] = ((const float4*)(qk + b * D))[threadIdx.x];
    __syncthreads();
    int wave = threadIdx.x >> 6, lane = threadIdx.x & 63;
    int s = s0 + wave;
    const float4* row = (const float4*)(key + ((size_t)b * SL + s) * D);
    float acc = 0.f;
    #pragma unroll
    for (int k = 0; k < 4; ++k) {
        float4 a  = row[lane + k * 64];
        float4 bq = qs[lane + k * 64];
        acc += a.x * bq.x + a.y * bq.y + a.z * bq.z + a.w * bq.w;
    }
    acc = wave_reduce_sum(acc);
    if (lane == 0) scores[b * SL + s] = acc * (1.0f / 32.0f);
}

// ---------------------------------------------------------------------------
// K4: softmax over s (4096) per batch, in place. 1024 threads, 16 blocks.
__global__ void softmax_kernel(float* __restrict__ sc) {
    int b = blockIdx.x;
    float* p = sc + b * SL;
    float4 v = ((float4*)p)[threadIdx.x];
    int wave = threadIdx.x >> 6, lane = threadIdx.x & 63;
    __shared__ float red[16];

    // max
    float m = fmaxf(fmaxf(v.x, v.y), fmaxf(v.z, v.w));
    #pragma unroll
    for (int mm = 32; mm >= 1; mm >>= 1) m = fmaxf(m, __shfl_xor(m, mm, 64));
    if (lane == 0) red[wave] = m;
    __syncthreads();
    if (threadIdx.x < 64) {
        float t = threadIdx.x < 16 ? red[threadIdx.x] : -INFINITY;
        #pragma unroll
        for (int mm = 8; mm >= 1; mm >>= 1) t = fmaxf(t, __shfl_xor(t, mm, 64));
        if (threadIdx.x == 0) red[0] = t;
    }
    __syncthreads();
    m = red[0];
    __syncthreads();

    // exp + sum
    float4 e;
    e.x = expf(v.x - m); e.y = expf(v.y - m);
    e.z = expf(v.z - m); e.w = expf(v.w - m);
    float s = e.x + e.y + e.z + e.w;
    s = wave_reduce_sum(s);
    if (lane == 0) red[wave] = s;
    __syncthreads();
    if (threadIdx.x < 64) {
        float t = threadIdx.x < 16 ? red[threadIdx.x] : 0.f;
        t = wave_reduce_sum(t);
        if (threadIdx.x == 0) red[0] = t;
    }
    __syncthreads();
    float inv = 1.0f / red[0];
    e.x *= inv; e.y *= inv; e.z *= inv; e.w *= inv;
    ((float4*)p)[threadIdx.x] = e;
}

// ---------------------------------------------------------------------------
// K5: partial weighted value sums (the 256 MB value stream).
__global__ void wval_partial_kernel(const float* __restrict__ value,
                                    const float* __restrict__ attn,
                                    float* __restrict__ partial) {
    int b  = blockIdx.x >> 6;
    int ch = blockIdx.x & 63;
    int s0 = ch * ROWS_PER_CH;
    const float4* vb = (const float4*)(value + ((size_t)b * SL + s0) * D);
    const float*  ab = attn + b * SL + s0;
    int t = threadIdx.x;
    float4 acc = {0.f, 0.f, 0.f, 0.f};
    #pragma unroll 4
    for (int r = 0; r < ROWS_PER_CH; ++r) {
        float a  = ab[r];
        float4 v = vb[(size_t)r * (D / 4) + t];
        acc.x += a * v.x; acc.y += a * v.y;
        acc.z += a * v.z; acc.w += a * v.w;
    }
    ((float4*)partial)[((size_t)b * NCH + ch) * (D / 4) + t] = acc;
}

// ---------------------------------------------------------------------------
// K6 (fused): wv[b,i] = sum_ch partial[b,ch,i];  out[b,o] = sum_i wv[b,i]*Wv[i,o]
__global__ void reduce_oproj_kernel(const float* __restrict__ partial,
                                    const float* __restrict__ Wv,
                                    float* __restrict__ out) {
    int b = blockIdx.x >> 2;
    int o = ((blockIdx.x & 3) << 8) + threadIdx.x;
    __shared__ float wl[D];
    for (int i = threadIdx.x; i < D; i += 256) {
        float acc = 0.f;
        const float* p = partial + (size_t)b * NCH * D + i;
        #pragma unroll 8
        for (int ch = 0; ch < NCH; ++ch) acc += p[(size_t)ch * D];
        wl[i] = acc;
    }
    __syncthreads();
    float acc = 0.f;
    #pragma unroll 4
    for (int i = 0; i < D; ++i) acc += wl[i] * Wv[i * D + o];
    out[b * D + o] = acc;
}

extern "C" void kernel_launch(void* const* d_in, const int* in_sizes, int n_in,
                              void* d_out, int out_size, void* d_ws, size_t ws_size,
                              hipStream_t stream) {
    const float* key   = (const float*)d_in[0];
    const float* query = (const float*)d_in[1];
    const float* value = (const float*)d_in[2];
    const float* Wk    = (const float*)d_in[3];
    const float* Wq    = (const float*)d_in[4];
    const float* Wv    = (const float*)d_in[5];
    float* out = (float*)d_out;

    // workspace layout (floats): all regions fully written before read
    float* ws      = (float*)d_ws;
    float* q       = ws;                        // NB*D      = 16384
    float* qk      = q  + NB * D;               // NB*D      = 16384
    float* sc      = qk + NB * D;               // NB*SL     = 65536
    float* partial = sc + NB * SL;              // NB*NCH*D  = 1048576

    qproj_kernel       <<<NB * 4,      256, 0, stream>>>(query, Wq, q);
    kvec_kernel        <<<NB * 4,      256, 0, stream>>>(Wk, q, qk);
    scores_kernel      <<<NB * SL / 4, 256, 0, stream>>>(key, qk, sc);
    softmax_kernel     <<<NB,         1024, 0, stream>>>(sc);
    wval_partial_kernel<<<NB * NCH,    256, 0, stream>>>(value, sc, partial);
    reduce_oproj_kernel<<<NB * 4,      256, 0, stream>>>(partial, Wv, out);
}